// Round 3
// baseline (273.422 us; speedup 1.0000x reference)
//
#include <hip/hip_runtime.h>

#define DT 0.02f

typedef __attribute__((ext_vector_type(8))) __bf16 bf16x8;
typedef __attribute__((ext_vector_type(4))) __bf16 bf16x4;
typedef __attribute__((ext_vector_type(4))) float  f32x4;

__device__ __forceinline__ float fast_tanh(float x){
    // tanh(x) = 1 - 2/(exp(2x)+1); exp(2x) = exp2(x * 2*log2(e))
    float e = __builtin_amdgcn_exp2f(x * 2.8853900817779268f);
    return 1.0f - 2.0f * __builtin_amdgcn_rcpf(e + 1.0f);
}
// swizzled LDS address for X[m][j] bf16 tiles (64 rows x 128 cols), byte = m*256 + j*2
__device__ __forceinline__ char* ldsx(char* base, int m, int j){
    return base + (((m << 8) + (j << 1)) ^ ((m & 7) << 4));
}

// Unified 128(hidden) x 64(sample) x 128(k) GEMM, TWO waves: wave w owns
// hidden rows [64w, 64w+64) x all 64 samples.  D[r][c] = sum_k Wg[r][k]*X[c][k].
// A (weights) from global (L2-hot, each row read by exactly one wave),
// B (activations) from swizzled LDS tile [c][k].
// FWD=1: Obuf[c][r] = tanh(D + bias[r])        (write-only)
// FWD=0: Obuf[c][r] = D * (1 - Obuf[c][r]^2)   (in-place mask)
template<int FWD>
__device__ __forceinline__ void hnn_gemm(const __bf16* __restrict__ Wg,
                                         char* Xbuf, char* Obuf,
                                         const float* __restrict__ bias,
                                         int w, int l)
{
    const int lr = l & 15, lg = l >> 4;
    const int rbase = w * 64;

    f32x4 acc[4][4];
    #pragma unroll
    for (int mt = 0; mt < 4; ++mt)
        #pragma unroll
        for (int nt = 0; nt < 4; ++nt) acc[mt][nt] = 0.0f;

    #pragma unroll
    for (int ks = 0; ks < 4; ++ks){
        const int kb = ks * 32 + lg * 8;
        bf16x8 a[4], b[4];
        #pragma unroll
        for (int mt = 0; mt < 4; ++mt)
            a[mt] = *(const bf16x8*)(Wg + ((rbase + mt * 16 + lr) << 7) + kb);
        #pragma unroll
        for (int nt = 0; nt < 4; ++nt)
            b[nt] = *(const bf16x8*)ldsx(Xbuf, nt * 16 + lr, kb);
        #pragma unroll
        for (int mt = 0; mt < 4; ++mt)
            #pragma unroll
            for (int nt = 0; nt < 4; ++nt)
                acc[mt][nt] = __builtin_amdgcn_mfma_f32_16x16x32_bf16(
                    a[mt], b[nt], acc[mt][nt], 0, 0, 0);
    }

    if (FWD){
        #pragma unroll
        for (int mt = 0; mt < 4; ++mt){
            const int j0 = rbase + mt * 16 + lg * 4;
            const f32x4 bv = *(const f32x4*)(bias + j0);
            #pragma unroll
            for (int nt = 0; nt < 4; ++nt){
                const int m = nt * 16 + lr;
                bf16x4 hv;
                #pragma unroll
                for (int jr = 0; jr < 4; ++jr)
                    hv[jr] = (__bf16)fast_tanh(acc[mt][nt][jr] + bv[jr]);
                *(bf16x4*)ldsx(Obuf, m, j0) = hv;
            }
        }
    } else {
        #pragma unroll
        for (int mt = 0; mt < 4; ++mt){
            const int j0 = rbase + mt * 16 + lg * 4;
            #pragma unroll
            for (int nt = 0; nt < 4; ++nt){
                const int m = nt * 16 + lr;
                bf16x4* hp = (bf16x4*)ldsx(Obuf, m, j0);
                bf16x4 hv = *hp, gv;
                #pragma unroll
                for (int jr = 0; jr < 4; ++jr){
                    float h = (float)hv[jr];
                    gv[jr] = (__bf16)(acc[mt][nt][jr] * (1.0f - h * h));
                }
                *hp = gv;
            }
        }
    }
}

// prep: cast W2/W3 fp32 -> bf16 into ws (unswizzled):
// [0]=Wt2 ([n][k]), [16384]=Wt3, [32768]=W2 ([i][j]), [49152]=W3
__global__ void hnn_prep(const float* __restrict__ W2, const float* __restrict__ W3,
                         __bf16* __restrict__ ws)
{
    int idx = blockIdx.x * 256 + threadIdx.x;   // 0..16383
    int k = idx >> 7, n = idx & 127;
    __bf16 v2 = (__bf16)W2[idx];
    __bf16 v3 = (__bf16)W3[idx];
    ws[n * 128 + k]         = v2;
    ws[16384 + n * 128 + k] = v3;
    ws[32768 + idx]         = v2;
    ws[49152 + idx]         = v3;
}

__global__ __launch_bounds__(128, 2)
void hnn_main(const float* __restrict__ q, const float* __restrict__ p,
              const float* __restrict__ Fx,
              const float* __restrict__ W1, const float* __restrict__ b1,
              const float* __restrict__ b2, const float* __restrict__ b3,
              const float* __restrict__ W4,
              const __bf16* __restrict__ ws,
              float* __restrict__ out)
{
    __shared__ char h1b[16384];       // [64][128] bf16, swizzled
    __shared__ char h2b[16384];
    __shared__ char h3b[16384];
    const int t = threadIdx.x;
    const int w = t >> 6, l = t & 63;
    const int lr = l & 15, lg = l >> 4;
    const long mg0 = (long)blockIdx.x * 64;

    // ---- phase 0: h1[m][j] = tanh(q*W1[0][j] + p*W1[1][j] + b1[j])
    // thread covers samples m = w*32 + i*4 + lg (i<8), j-block j0 = lr*8
    {
        const int j0 = lr * 8;
        f32x4 wq0 = *(const f32x4*)(W1 + j0),       wq1 = *(const f32x4*)(W1 + j0 + 4);
        f32x4 wp0 = *(const f32x4*)(W1 + 128 + j0), wp1 = *(const f32x4*)(W1 + 128 + j0 + 4);
        f32x4 bb0 = *(const f32x4*)(b1 + j0),       bb1 = *(const f32x4*)(b1 + j0 + 4);
        #pragma unroll
        for (int i = 0; i < 8; ++i){
            int m = w * 32 + i * 4 + lg;
            float qq = q[mg0 + m], pp = p[mg0 + m];
            bf16x8 hv;
            #pragma unroll
            for (int u = 0; u < 4; ++u){
                hv[u]     = (__bf16)fast_tanh(fmaf(qq, wq0[u], fmaf(pp, wp0[u], bb0[u])));
                hv[4 + u] = (__bf16)fast_tanh(fmaf(qq, wq1[u], fmaf(pp, wp1[u], bb1[u])));
            }
            *(bf16x8*)ldsx(h1b, m, j0) = hv;
        }
    }
    __syncthreads();
    hnn_gemm<1>(ws,         h1b, h2b, b2, w, l);   // h2 = tanh(h1@W2 + b2)
    __syncthreads();
    hnn_gemm<1>(ws + 16384, h2b, h3b, b3, w, l);   // h3 = tanh(h2@W3 + b3)
    __syncthreads();

    // ---- phase 3: g3[m][j] = W4[j] * (1 - h3[m][j]^2), in place
    {
        const int j0 = lr * 8;
        f32x4 w40 = *(const f32x4*)(W4 + j0), w41 = *(const f32x4*)(W4 + j0 + 4);
        #pragma unroll
        for (int i = 0; i < 8; ++i){
            int m = w * 32 + i * 4 + lg;
            bf16x8* ptr = (bf16x8*)ldsx(h3b, m, j0);
            bf16x8 hv = *ptr, gv;
            #pragma unroll
            for (int u = 0; u < 4; ++u){
                float h0 = (float)hv[u],     h1v = (float)hv[4 + u];
                gv[u]     = (__bf16)(w40[u] * (1.0f - h0 * h0));
                gv[4 + u] = (__bf16)(w41[u] * (1.0f - h1v * h1v));
            }
            *ptr = gv;
        }
    }
    __syncthreads();
    hnn_gemm<0>(ws + 49152, h3b, h2b, nullptr, w, l);  // g2 = (g3 @ W3^T)*(1-h2^2) in h2b
    __syncthreads();
    hnn_gemm<0>(ws + 32768, h2b, h1b, nullptr, w, l);  // g1 = (g2 @ W2^T)*(1-h1^2) in h1b
    __syncthreads();

    // ---- phase 6: dHdq[m] = sum_j g1[m][j]*W1[0][j], dHdp likewise
    // thread t: sample m = t&63, j-half q4 = t>>6 (64 j's each)
    {
        const int m = t & 63, q4 = t >> 6;
        float sdq = 0.f, sdp = 0.f;
        #pragma unroll
        for (int i = 0; i < 8; ++i){
            int j0 = q4 * 64 + i * 8;
            bf16x8 gv = *(const bf16x8*)ldsx(h1b, m, j0);
            f32x4 wq0 = *(const f32x4*)(W1 + j0),       wq1 = *(const f32x4*)(W1 + j0 + 4);
            f32x4 wp0 = *(const f32x4*)(W1 + 128 + j0), wp1 = *(const f32x4*)(W1 + 128 + j0 + 4);
            #pragma unroll
            for (int u = 0; u < 4; ++u){
                float g0 = (float)gv[u], g1v = (float)gv[4 + u];
                sdq = fmaf(g0, wq0[u], fmaf(g1v, wq1[u], sdq));
                sdp = fmaf(g0, wp0[u], fmaf(g1v, wp1[u], sdp));
            }
        }
        float2* red = (float2*)h2b;                 // h2b dead; reuse as reduction buffer
        red[m * 2 + q4] = make_float2(sdq, sdp);
    }
    __syncthreads();
    if (t < 64){
        const float2* red = (const float2*)h2b;
        float2 r0 = red[t * 2 + 0], r1 = red[t * 2 + 1];
        float dq = r0.x + r1.x;
        float dp = r0.y + r1.y;
        long gm = mg0 + t;
        float2 o;
        o.x = DT * dp;                      // dq_dt = dH/dp
        o.y = DT * (-dq + Fx[gm]);          // dp_dt = -dH/dq + F_ext
        *(float2*)(out + gm * 2) = o;
    }
}

extern "C" void kernel_launch(void* const* d_in, const int* in_sizes, int n_in,
                              void* d_out, int out_size, void* d_ws, size_t ws_size,
                              hipStream_t stream) {
    const float* q   = (const float*)d_in[0];
    const float* p   = (const float*)d_in[1];
    const float* Fx  = (const float*)d_in[2];
    const float* W1  = (const float*)d_in[3];
    const float* b1  = (const float*)d_in[4];
    const float* W2  = (const float*)d_in[5];
    const float* b2  = (const float*)d_in[6];
    const float* W3  = (const float*)d_in[7];
    const float* b3  = (const float*)d_in[8];
    const float* W4  = (const float*)d_in[9];
    // d_in[10] = b4 (unused: gradients do not depend on it)
    __bf16* ws = (__bf16*)d_ws;
    float* out = (float*)d_out;

    (void)in_sizes; (void)n_in; (void)out_size; (void)ws_size;

    hnn_prep<<<64, 256, 0, stream>>>(W2, W3, ws);
    hnn_main<<<8192, 128, 0, stream>>>(q, p, Fx, W1, b1, b2, b3, W4, ws, out);
}

// Round 6
// 257.808 us; speedup vs baseline: 1.0606x; 1.0606x over previous
//
#include <hip/hip_runtime.h>

#define DT 0.02f

typedef __attribute__((ext_vector_type(8))) __bf16 bf16x8;
typedef __attribute__((ext_vector_type(4))) __bf16 bf16x4;
typedef __attribute__((ext_vector_type(4))) float  f32x4;

__device__ __forceinline__ float fast_tanh(float x){
    // tanh(x) = 1 - 2/(exp(2x)+1); exp(2x) = exp2(x * 2*log2(e))
    float e = __builtin_amdgcn_exp2f(x * 2.8853900817779268f);
    return 1.0f - 2.0f * __builtin_amdgcn_rcpf(e + 1.0f);
}
// swizzled LDS address for X[m][j] bf16 tiles (64 rows x 128 cols), byte = m*256 + j*2
__device__ __forceinline__ char* ldsx(char* base, int m, int j){
    return base + (((m << 8) + (j << 1)) ^ ((m & 7) << 4));
}

// 128(hidden) x 64(sample) x 128(k) GEMM, FOUR waves: wave w owns hidden rows
// [32w, 32w+32) x all 64 samples.  D[r][c] = sum_k Wg[r][k]*X[c][k].
// A (weights) from global (L1/L2-hot), B (activations) from swizzled LDS tile [c][k].
// MODE 1: Obuf[c][r] = tanh(D + bias[r])            (write-only)
// MODE 0: Obuf[c][r] = D * (1 - Obuf[c][r]^2)       (in-place mask RMW)
// MODE 2: Obuf[c][r] = D * (1 - h1(c,r)^2)          (mask recomputed from q,p,W1,b1)
template<int MODE>
__device__ __forceinline__ void hnn_gemm(const __bf16* __restrict__ Wg,
                                         char* Xbuf, char* Obuf,
                                         const float* __restrict__ bias,
                                         const float* __restrict__ W1,
                                         const float* __restrict__ b1,
                                         const float* __restrict__ qv,
                                         const float* __restrict__ pv,
                                         int w, int l)
{
    const int lr = l & 15, lg = l >> 4;
    const int rbase = w * 32;

    f32x4 acc[2][4];
    #pragma unroll
    for (int mt = 0; mt < 2; ++mt)
        #pragma unroll
        for (int nt = 0; nt < 4; ++nt) acc[mt][nt] = 0.0f;

    #pragma unroll
    for (int ks = 0; ks < 4; ++ks){
        const int kb = ks * 32 + lg * 8;
        bf16x8 a[2], b[4];
        #pragma unroll
        for (int mt = 0; mt < 2; ++mt)
            a[mt] = *(const bf16x8*)(Wg + ((rbase + mt * 16 + lr) << 7) + kb);
        #pragma unroll
        for (int nt = 0; nt < 4; ++nt)
            b[nt] = *(const bf16x8*)ldsx(Xbuf, nt * 16 + lr, kb);
        #pragma unroll
        for (int mt = 0; mt < 2; ++mt)
            #pragma unroll
            for (int nt = 0; nt < 4; ++nt)
                acc[mt][nt] = __builtin_amdgcn_mfma_f32_16x16x32_bf16(
                    a[mt], b[nt], acc[mt][nt], 0, 0, 0);
    }

    if (MODE == 1){
        #pragma unroll
        for (int mt = 0; mt < 2; ++mt){
            const int j0 = rbase + mt * 16 + lg * 4;
            const f32x4 bv = *(const f32x4*)(bias + j0);
            #pragma unroll
            for (int nt = 0; nt < 4; ++nt){
                const int m = nt * 16 + lr;
                bf16x4 hv;
                #pragma unroll
                for (int jr = 0; jr < 4; ++jr)
                    hv[jr] = (__bf16)fast_tanh(acc[mt][nt][jr] + bv[jr]);
                *(bf16x4*)ldsx(Obuf, m, j0) = hv;
            }
        }
    } else if (MODE == 0){
        #pragma unroll
        for (int mt = 0; mt < 2; ++mt){
            const int j0 = rbase + mt * 16 + lg * 4;
            #pragma unroll
            for (int nt = 0; nt < 4; ++nt){
                const int m = nt * 16 + lr;
                bf16x4* hp = (bf16x4*)ldsx(Obuf, m, j0);
                bf16x4 hv = *hp, gv;
                #pragma unroll
                for (int jr = 0; jr < 4; ++jr){
                    float h = (float)hv[jr];
                    gv[jr] = (__bf16)(acc[mt][nt][jr] * (1.0f - h * h));
                }
                *hp = gv;
            }
        }
    } else {
        float qq[4], pp[4];
        #pragma unroll
        for (int nt = 0; nt < 4; ++nt){
            qq[nt] = qv[nt * 16 + lr];
            pp[nt] = pv[nt * 16 + lr];
        }
        #pragma unroll
        for (int mt = 0; mt < 2; ++mt){
            const int j0 = rbase + mt * 16 + lg * 4;
            const f32x4 wq = *(const f32x4*)(W1 + j0);
            const f32x4 wp = *(const f32x4*)(W1 + 128 + j0);
            const f32x4 bb = *(const f32x4*)(b1 + j0);
            #pragma unroll
            for (int nt = 0; nt < 4; ++nt){
                const int m = nt * 16 + lr;
                bf16x4 gv;
                #pragma unroll
                for (int jr = 0; jr < 4; ++jr){
                    float h = fast_tanh(fmaf(qq[nt], wq[jr], fmaf(pp[nt], wp[jr], bb[jr])));
                    gv[jr] = (__bf16)(acc[mt][nt][jr] * (1.0f - h * h));
                }
                *(bf16x4*)ldsx(Obuf, m, j0) = gv;
            }
        }
    }
}

// prep: cast W2/W3 fp32 -> bf16 into ws (unswizzled):
// [0]=Wt2 ([n][k]), [16384]=Wt3, [32768]=W2 ([i][j]), [49152]=W3
__global__ void hnn_prep(const float* __restrict__ W2, const float* __restrict__ W3,
                         __bf16* __restrict__ ws)
{
    int idx = blockIdx.x * 256 + threadIdx.x;   // 0..16383
    int k = idx >> 7, n = idx & 127;
    __bf16 v2 = (__bf16)W2[idx];
    __bf16 v3 = (__bf16)W3[idx];
    ws[n * 128 + k]         = v2;
    ws[16384 + n * 128 + k] = v3;
    ws[32768 + idx]         = v2;
    ws[49152 + idx]         = v3;
}

__global__ __launch_bounds__(256, 5)
void hnn_main(const float* __restrict__ q, const float* __restrict__ p,
              const float* __restrict__ Fx,
              const float* __restrict__ W1, const float* __restrict__ b1,
              const float* __restrict__ b2, const float* __restrict__ b3,
              const float* __restrict__ W4,
              const __bf16* __restrict__ ws,
              float* __restrict__ out)
{
    __shared__ char bufA[16384];      // [64][128] bf16, swizzled
    __shared__ char bufB[16384];
    const int t = threadIdx.x;
    const int w = t >> 6, l = t & 63;
    const int lr = l & 15, lg = l >> 4;
    const long mg0 = (long)blockIdx.x * 64;

    // ---- phase 0: h1[m][j] = tanh(q*W1[0][j] + p*W1[1][j] + b1[j]) -> bufA
    // thread covers samples m = w*16 + i*4 + lg (i<4), j-block j0 = lr*8
    {
        const int j0 = lr * 8;
        f32x4 wq0 = *(const f32x4*)(W1 + j0),       wq1 = *(const f32x4*)(W1 + j0 + 4);
        f32x4 wp0 = *(const f32x4*)(W1 + 128 + j0), wp1 = *(const f32x4*)(W1 + 128 + j0 + 4);
        f32x4 bb0 = *(const f32x4*)(b1 + j0),       bb1 = *(const f32x4*)(b1 + j0 + 4);
        #pragma unroll
        for (int i = 0; i < 4; ++i){
            int m = w * 16 + i * 4 + lg;
            float qq = q[mg0 + m], pp = p[mg0 + m];
            bf16x8 hv;
            #pragma unroll
            for (int u = 0; u < 4; ++u){
                hv[u]     = (__bf16)fast_tanh(fmaf(qq, wq0[u], fmaf(pp, wp0[u], bb0[u])));
                hv[4 + u] = (__bf16)fast_tanh(fmaf(qq, wq1[u], fmaf(pp, wp1[u], bb1[u])));
            }
            *(bf16x8*)ldsx(bufA, m, j0) = hv;
        }
    }
    __syncthreads();
    hnn_gemm<1>(ws,         bufA, bufB, b2, nullptr, nullptr, nullptr, nullptr, w, l); // h2 -> B
    __syncthreads();
    hnn_gemm<1>(ws + 16384, bufB, bufA, b3, nullptr, nullptr, nullptr, nullptr, w, l); // h3 -> A
    __syncthreads();

    // ---- phase 3: g3[m][j] = W4[j] * (1 - h3[m][j]^2), in place in bufA
    {
        const int j0 = lr * 8;
        f32x4 w40 = *(const f32x4*)(W4 + j0), w41 = *(const f32x4*)(W4 + j0 + 4);
        #pragma unroll
        for (int i = 0; i < 4; ++i){
            int m = w * 16 + i * 4 + lg;
            bf16x8* ptr = (bf16x8*)ldsx(bufA, m, j0);
            bf16x8 hv = *ptr, gv;
            #pragma unroll
            for (int u = 0; u < 4; ++u){
                float h0 = (float)hv[u],     h1v = (float)hv[4 + u];
                gv[u]     = (__bf16)(w40[u] * (1.0f - h0 * h0));
                gv[4 + u] = (__bf16)(w41[u] * (1.0f - h1v * h1v));
            }
            *ptr = gv;
        }
    }
    __syncthreads();
    // g2 = (g3 @ W3^T)*(1-h2^2): B-frags from bufA(g3), in-place mask RMW in bufB
    hnn_gemm<0>(ws + 49152, bufA, bufB, nullptr, nullptr, nullptr, nullptr, nullptr, w, l);
    __syncthreads();
    // g1 = (g2 @ W2^T)*(1-h1^2): B-frags from bufB(g2), h1 recomputed, out -> bufA
    hnn_gemm<2>(ws + 32768, bufB, bufA, nullptr, W1, b1, q + mg0, p + mg0, w, l);
    __syncthreads();

    // ---- phase 6: dHdq[m] = sum_j g1[m][j]*W1[0][j], dHdp likewise
    // thread t: sample m = t&63, j-quarter q4 = t>>6 (32 j's each)
    {
        const int m = t & 63, q4 = t >> 6;
        float sdq = 0.f, sdp = 0.f;
        #pragma unroll
        for (int i = 0; i < 4; ++i){
            int j0 = q4 * 32 + i * 8;
            bf16x8 gv = *(const bf16x8*)ldsx(bufA, m, j0);
            f32x4 wq0 = *(const f32x4*)(W1 + j0),       wq1 = *(const f32x4*)(W1 + j0 + 4);
            f32x4 wp0 = *(const f32x4*)(W1 + 128 + j0), wp1 = *(const f32x4*)(W1 + 128 + j0 + 4);
            #pragma unroll
            for (int u = 0; u < 4; ++u){
                float g0 = (float)gv[u], g1v = (float)gv[4 + u];
                sdq = fmaf(g0, wq0[u], fmaf(g1v, wq1[u], sdq));
                sdp = fmaf(g0, wp0[u], fmaf(g1v, wp1[u], sdp));
            }
        }
        float2* red = (float2*)bufB;                // bufB dead; reuse as reduction buffer
        red[m * 4 + q4] = make_float2(sdq, sdp);
    }
    __syncthreads();
    if (t < 64){
        const float2* red = (const float2*)bufB;
        float2 r0 = red[t * 4 + 0], r1 = red[t * 4 + 1];
        float2 r2 = red[t * 4 + 2], r3 = red[t * 4 + 3];
        float dq = r0.x + r1.x + r2.x + r3.x;
        float dp = r0.y + r1.y + r2.y + r3.y;
        long gm = mg0 + t;
        float2 o;
        o.x = DT * dp;                      // dq_dt = dH/dp
        o.y = DT * (-dq + Fx[gm]);          // dp_dt = -dH/dq + F_ext
        *(float2*)(out + gm * 2) = o;
    }
}

extern "C" void kernel_launch(void* const* d_in, const int* in_sizes, int n_in,
                              void* d_out, int out_size, void* d_ws, size_t ws_size,
                              hipStream_t stream) {
    const float* q   = (const float*)d_in[0];
    const float* p   = (const float*)d_in[1];
    const float* Fx  = (const float*)d_in[2];
    const float* W1  = (const float*)d_in[3];
    const float* b1  = (const float*)d_in[4];
    const float* W2  = (const float*)d_in[5];
    const float* b2  = (const float*)d_in[6];
    const float* W3  = (const float*)d_in[7];
    const float* b3  = (const float*)d_in[8];
    const float* W4  = (const float*)d_in[9];
    // d_in[10] = b4 (unused: gradients do not depend on it)
    __bf16* ws = (__bf16*)d_ws;
    float* out = (float*)d_out;

    (void)in_sizes; (void)n_in; (void)out_size; (void)ws_size;

    hnn_prep<<<64, 256, 0, stream>>>(W2, W3, ws);
    hnn_main<<<8192, 256, 0, stream>>>(q, p, Fx, W1, b1, b2, b3, W4, ws, out);
}

// Round 8
// 238.905 us; speedup vs baseline: 1.1445x; 1.0791x over previous
//
#include <hip/hip_runtime.h>

#define DT 0.02f

typedef __attribute__((ext_vector_type(8))) __bf16 bf16x8;
typedef __attribute__((ext_vector_type(4))) __bf16 bf16x4;
typedef __attribute__((ext_vector_type(4))) float  f32x4;

__device__ __forceinline__ float fast_tanh(float x){
    // tanh(x) = 1 - 2/(exp(2x)+1); exp(2x) = exp2(x * 2*log2(e))
    float e = __builtin_amdgcn_exp2f(x * 2.8853900817779268f);
    return 1.0f - 2.0f * __builtin_amdgcn_rcpf(e + 1.0f);
}
// swizzled LDS address for X[m][j] bf16 tiles (64 rows x 128 cols), byte = m*256 + j*2
__device__ __forceinline__ char* ldsx(char* base, int m, int j){
    return base + (((m << 8) + (j << 1)) ^ ((m & 7) << 4));
}

// 128(hidden) x 64(sample) x 128(k) GEMM, FOUR waves: wave w owns hidden rows
// [32w, 32w+32) x all 64 samples.  D[r][c] = sum_k Wg[r][k]*X[c][k].
// A (weights) from global (L1/L2-hot), B (activations) from swizzled LDS tile [c][k].
// MODE 1: Obuf[c][r] = tanh(D + bias[r])            (write-only)
// MODE 0: Obuf[c][r] = D * (1 - Obuf[c][r]^2)       (in-place mask RMW)
// MODE 2: Obuf[c][r] = D * (1 - h1(c,r)^2)          (mask recomputed from q,p,W1,b1)
template<int MODE>
__device__ __forceinline__ void hnn_gemm(const __bf16* __restrict__ Wg,
                                         char* Xbuf, char* Obuf,
                                         const float* __restrict__ bias,
                                         const float* __restrict__ W1,
                                         const float* __restrict__ b1,
                                         const float* __restrict__ qv,
                                         const float* __restrict__ pv,
                                         int w, int l)
{
    const int lr = l & 15, lg = l >> 4;
    const int rbase = w * 32;

    f32x4 acc[2][4];
    #pragma unroll
    for (int mt = 0; mt < 2; ++mt)
        #pragma unroll
        for (int nt = 0; nt < 4; ++nt) acc[mt][nt] = 0.0f;

    #pragma unroll
    for (int ks = 0; ks < 4; ++ks){
        const int kb = ks * 32 + lg * 8;
        bf16x8 a[2], b[4];
        #pragma unroll
        for (int mt = 0; mt < 2; ++mt)
            a[mt] = *(const bf16x8*)(Wg + ((rbase + mt * 16 + lr) << 7) + kb);
        #pragma unroll
        for (int nt = 0; nt < 4; ++nt)
            b[nt] = *(const bf16x8*)ldsx(Xbuf, nt * 16 + lr, kb);
        #pragma unroll
        for (int mt = 0; mt < 2; ++mt)
            #pragma unroll
            for (int nt = 0; nt < 4; ++nt)
                acc[mt][nt] = __builtin_amdgcn_mfma_f32_16x16x32_bf16(
                    a[mt], b[nt], acc[mt][nt], 0, 0, 0);
    }

    if (MODE == 1){
        #pragma unroll
        for (int mt = 0; mt < 2; ++mt){
            const int j0 = rbase + mt * 16 + lg * 4;
            const f32x4 bv = *(const f32x4*)(bias + j0);
            #pragma unroll
            for (int nt = 0; nt < 4; ++nt){
                const int m = nt * 16 + lr;
                bf16x4 hv;
                #pragma unroll
                for (int jr = 0; jr < 4; ++jr)
                    hv[jr] = (__bf16)fast_tanh(acc[mt][nt][jr] + bv[jr]);
                *(bf16x4*)ldsx(Obuf, m, j0) = hv;
            }
        }
    } else if (MODE == 0){
        #pragma unroll
        for (int mt = 0; mt < 2; ++mt){
            const int j0 = rbase + mt * 16 + lg * 4;
            #pragma unroll
            for (int nt = 0; nt < 4; ++nt){
                const int m = nt * 16 + lr;
                bf16x4* hp = (bf16x4*)ldsx(Obuf, m, j0);
                bf16x4 hv = *hp, gv;
                #pragma unroll
                for (int jr = 0; jr < 4; ++jr){
                    float h = (float)hv[jr];
                    gv[jr] = (__bf16)(acc[mt][nt][jr] * (1.0f - h * h));
                }
                *hp = gv;
            }
        }
    } else {
        float qq[4], pp[4];
        #pragma unroll
        for (int nt = 0; nt < 4; ++nt){
            qq[nt] = qv[nt * 16 + lr];
            pp[nt] = pv[nt * 16 + lr];
        }
        #pragma unroll
        for (int mt = 0; mt < 2; ++mt){
            const int j0 = rbase + mt * 16 + lg * 4;
            const f32x4 wq = *(const f32x4*)(W1 + j0);
            const f32x4 wp = *(const f32x4*)(W1 + 128 + j0);
            const f32x4 bb = *(const f32x4*)(b1 + j0);
            #pragma unroll
            for (int nt = 0; nt < 4; ++nt){
                const int m = nt * 16 + lr;
                bf16x4 gv;
                #pragma unroll
                for (int jr = 0; jr < 4; ++jr){
                    float h = fast_tanh(fmaf(qq[nt], wq[jr], fmaf(pp[nt], wp[jr], bb[jr])));
                    gv[jr] = (__bf16)(acc[mt][nt][jr] * (1.0f - h * h));
                }
                *(bf16x4*)ldsx(Obuf, m, j0) = gv;
            }
        }
    }
}

// prep: cast W2/W3 fp32 -> bf16 into ws (unswizzled):
// [0]=Wt2 ([n][k]), [16384]=Wt3, [32768]=W2 ([i][j]), [49152]=W3
__global__ void hnn_prep(const float* __restrict__ W2, const float* __restrict__ W3,
                         __bf16* __restrict__ ws)
{
    int idx = blockIdx.x * 256 + threadIdx.x;   // 0..16383
    int k = idx >> 7, n = idx & 127;
    __bf16 v2 = (__bf16)W2[idx];
    __bf16 v3 = (__bf16)W3[idx];
    ws[n * 128 + k]         = v2;
    ws[16384 + n * 128 + k] = v3;
    ws[32768 + idx]         = v2;
    ws[49152 + idx]         = v3;
}

__global__ __launch_bounds__(256, 4)
void hnn_main(const float* __restrict__ q, const float* __restrict__ p,
              const float* __restrict__ Fx,
              const float* __restrict__ W1, const float* __restrict__ b1,
              const float* __restrict__ b2, const float* __restrict__ b3,
              const float* __restrict__ W4,
              const __bf16* __restrict__ ws,
              float* __restrict__ out)
{
    __shared__ char bufA[16384];      // [64][128] bf16, swizzled
    __shared__ char bufB[16384];
    const int t = threadIdx.x;
    const int w = t >> 6, l = t & 63;
    const int lr = l & 15, lg = l >> 4;
    const long mg0 = (long)blockIdx.x * 64;

    // ---- phase 0: h1[m][j] = tanh(q*W1[0][j] + p*W1[1][j] + b1[j]) -> bufA
    // thread covers samples m = w*16 + i*4 + lg (i<4), j-block j0 = lr*8
    {
        const int j0 = lr * 8;
        f32x4 wq0 = *(const f32x4*)(W1 + j0),       wq1 = *(const f32x4*)(W1 + j0 + 4);
        f32x4 wp0 = *(const f32x4*)(W1 + 128 + j0), wp1 = *(const f32x4*)(W1 + 128 + j0 + 4);
        f32x4 bb0 = *(const f32x4*)(b1 + j0),       bb1 = *(const f32x4*)(b1 + j0 + 4);
        #pragma unroll
        for (int i = 0; i < 4; ++i){
            int m = w * 16 + i * 4 + lg;
            float qq = q[mg0 + m], pp = p[mg0 + m];
            bf16x8 hv;
            #pragma unroll
            for (int u = 0; u < 4; ++u){
                hv[u]     = (__bf16)fast_tanh(fmaf(qq, wq0[u], fmaf(pp, wp0[u], bb0[u])));
                hv[4 + u] = (__bf16)fast_tanh(fmaf(qq, wq1[u], fmaf(pp, wp1[u], bb1[u])));
            }
            *(bf16x8*)ldsx(bufA, m, j0) = hv;
        }
    }
    __syncthreads();
    hnn_gemm<1>(ws,         bufA, bufB, b2, nullptr, nullptr, nullptr, nullptr, w, l); // h2 -> B
    __syncthreads();
    hnn_gemm<1>(ws + 16384, bufB, bufA, b3, nullptr, nullptr, nullptr, nullptr, w, l); // h3 -> A
    __syncthreads();

    // ---- phase 3: g3[m][j] = W4[j] * (1 - h3[m][j]^2), in place in bufA
    {
        const int j0 = lr * 8;
        f32x4 w40 = *(const f32x4*)(W4 + j0), w41 = *(const f32x4*)(W4 + j0 + 4);
        #pragma unroll
        for (int i = 0; i < 4; ++i){
            int m = w * 16 + i * 4 + lg;
            bf16x8* ptr = (bf16x8*)ldsx(bufA, m, j0);
            bf16x8 hv = *ptr, gv;
            #pragma unroll
            for (int u = 0; u < 4; ++u){
                float h0 = (float)hv[u],     h1v = (float)hv[4 + u];
                gv[u]     = (__bf16)(w40[u] * (1.0f - h0 * h0));
                gv[4 + u] = (__bf16)(w41[u] * (1.0f - h1v * h1v));
            }
            *ptr = gv;
        }
    }
    __syncthreads();
    // g2 = (g3 @ W3^T)*(1-h2^2): B-frags from bufA(g3), in-place mask RMW in bufB
    hnn_gemm<0>(ws + 49152, bufA, bufB, nullptr, nullptr, nullptr, nullptr, nullptr, w, l);
    __syncthreads();
    // g1 = (g2 @ W2^T)*(1-h1^2): B-frags from bufB(g2), h1 recomputed, out -> bufA
    hnn_gemm<2>(ws + 32768, bufB, bufA, nullptr, W1, b1, q + mg0, p + mg0, w, l);
    __syncthreads();

    // ---- phase 6: dHdq[m] = sum_j g1[m][j]*W1[0][j], dHdp likewise
    // thread t: sample m = t&63, j-quarter q4 = t>>6 (32 j's each)
    {
        const int m = t & 63, q4 = t >> 6;
        float sdq = 0.f, sdp = 0.f;
        #pragma unroll
        for (int i = 0; i < 4; ++i){
            int j0 = q4 * 32 + i * 8;
            bf16x8 gv = *(const bf16x8*)ldsx(bufA, m, j0);
            f32x4 wq0 = *(const f32x4*)(W1 + j0),       wq1 = *(const f32x4*)(W1 + j0 + 4);
            f32x4 wp0 = *(const f32x4*)(W1 + 128 + j0), wp1 = *(const f32x4*)(W1 + 128 + j0 + 4);
            #pragma unroll
            for (int u = 0; u < 4; ++u){
                float g0 = (float)gv[u], g1v = (float)gv[4 + u];
                sdq = fmaf(g0, wq0[u], fmaf(g1v, wq1[u], sdq));
                sdp = fmaf(g0, wp0[u], fmaf(g1v, wp1[u], sdp));
            }
        }
        float2* red = (float2*)bufB;                // bufB dead; reuse as reduction buffer
        red[m * 4 + q4] = make_float2(sdq, sdp);
    }
    __syncthreads();
    if (t < 64){
        const float2* red = (const float2*)bufB;
        float2 r0 = red[t * 4 + 0], r1 = red[t * 4 + 1];
        float2 r2 = red[t * 4 + 2], r3 = red[t * 4 + 3];
        float dq = r0.x + r1.x + r2.x + r3.x;
        float dp = r0.y + r1.y + r2.y + r3.y;
        long gm = mg0 + t;
        float2 o;
        o.x = DT * dp;                      // dq_dt = dH/dp
        o.y = DT * (-dq + Fx[gm]);          // dp_dt = -dH/dq + F_ext
        *(float2*)(out + gm * 2) = o;
    }
}

extern "C" void kernel_launch(void* const* d_in, const int* in_sizes, int n_in,
                              void* d_out, int out_size, void* d_ws, size_t ws_size,
                              hipStream_t stream) {
    const float* q   = (const float*)d_in[0];
    const float* p   = (const float*)d_in[1];
    const float* Fx  = (const float*)d_in[2];
    const float* W1  = (const float*)d_in[3];
    const float* b1  = (const float*)d_in[4];
    const float* W2  = (const float*)d_in[5];
    const float* b2  = (const float*)d_in[6];
    const float* W3  = (const float*)d_in[7];
    const float* b3  = (const float*)d_in[8];
    const float* W4  = (const float*)d_in[9];
    // d_in[10] = b4 (unused: gradients do not depend on it)
    __bf16* ws = (__bf16*)d_ws;
    float* out = (float*)d_out;

    (void)in_sizes; (void)n_in; (void)out_size; (void)ws_size;

    hnn_prep<<<64, 256, 0, stream>>>(W2, W3, ws);
    hnn_main<<<8192, 256, 0, stream>>>(q, p, Fx, W1, b1, b2, b3, W4, ws, out);
}